// Round 1
// baseline (436.758 us; speedup 1.0000x reference)
//
#include <hip/hip_runtime.h>

#define DIM 128

// ---------------------------------------------------------------------------
// CSR build: count degrees -> exclusive scan -> fill column list
// ---------------------------------------------------------------------------

__global__ __launch_bounds__(256) void k_count(const int* __restrict__ dst,
                                               int* __restrict__ deg, int E) {
  int e = blockIdx.x * 256 + threadIdx.x;
  if (e < E) atomicAdd(&deg[dst[e]], 1);
}

// Single-block exclusive scan over n=50000: each thread serial-sums a chunk,
// 1024-wide Hillis-Steele scan of partials in LDS, then re-walk writing prefix.
__global__ __launch_bounds__(1024) void k_scan(const int* __restrict__ deg,
                                               int* __restrict__ rowptr,
                                               int* __restrict__ cursor, int n) {
  __shared__ int part[1024];
  int t = threadIdx.x;
  int chunk = (n + 1023) >> 10;
  int start = t * chunk;
  int end = start + chunk; if (end > n) end = n;
  int sum = 0;
  for (int i = start; i < end; ++i) sum += deg[i];
  part[t] = sum;
  __syncthreads();
  for (int off = 1; off < 1024; off <<= 1) {
    int v = (t >= off) ? part[t - off] : 0;
    __syncthreads();
    part[t] += v;
    __syncthreads();
  }
  int run = part[t] - sum;  // exclusive prefix of this thread's chunk
  for (int i = start; i < end; ++i) {
    rowptr[i] = run;
    cursor[i] = run;
    run += deg[i];
  }
  if (t == 1023) rowptr[n] = part[1023];
}

__global__ __launch_bounds__(256) void k_fill(const int* __restrict__ src,
                                              const int* __restrict__ dst,
                                              int* __restrict__ cursor,
                                              int* __restrict__ col, int E) {
  int e = blockIdx.x * 256 + threadIdx.x;
  if (e < E) {
    int p = atomicAdd(&cursor[dst[e]], 1);
    col[p] = src[e];
  }
}

// ---------------------------------------------------------------------------
// Layer-1 aggregation: agg[i] = mean_{j in N(i)} x[j]   (CSR gather-sum)
// 2 nodes per 256-thread block; 128 lanes = one feature row (coalesced).
// 4-deep unroll for load-latency ILP.
// ---------------------------------------------------------------------------
__global__ __launch_bounds__(256) void k_agg(const float* __restrict__ x,
                                             const int* __restrict__ rowptr,
                                             const int* __restrict__ col,
                                             float* __restrict__ agg, int n) {
  int node = blockIdx.x * 2 + (threadIdx.x >> 7);
  int c = threadIdx.x & 127;
  if (node >= n) return;
  int b = rowptr[node], e = rowptr[node + 1];
  float a0 = 0.f, a1 = 0.f, a2 = 0.f, a3 = 0.f;
  int i = b;
  for (; i + 4 <= e; i += 4) {
    int c0 = col[i], c1 = col[i + 1], c2 = col[i + 2], c3 = col[i + 3];
    a0 += x[(size_t)c0 * DIM + c];
    a1 += x[(size_t)c1 * DIM + c];
    a2 += x[(size_t)c2 * DIM + c];
    a3 += x[(size_t)c3 * DIM + c];
  }
  for (; i < e; ++i) a0 += x[(size_t)col[i] * DIM + c];
  float inv = 1.0f / (float)max(e - b, 1);
  agg[(size_t)node * DIM + c] = (a0 + a1 + a2 + a3) * inv;
}

// ---------------------------------------------------------------------------
// Fused layer-1 GEMM + layer-2 projections:
//   h[n] = relu(agg[n] @ W1_l + x[n] @ W1_r + b1)      (h kept in registers)
//   s[n] = h[n] . w2_l ;  t[n] = h[n] . w2_r
// Tile: 64 nodes x 128 cols per 256-thread block; thread = 8 nodes x 4 cols.
// W read through L2 (128 KB, resident); u rows broadcast loads.
// ---------------------------------------------------------------------------
__global__ __launch_bounds__(256) void k_gemm(const float* __restrict__ agg,
                                              const float* __restrict__ x,
                                              const float* __restrict__ W1l,
                                              const float* __restrict__ W1r,
                                              const float* __restrict__ b1,
                                              const float* __restrict__ w2l,
                                              const float* __restrict__ w2r,
                                              float* __restrict__ sbuf,
                                              float* __restrict__ tbuf, int n) {
  int tid = threadIdx.x;
  int cg = tid & 31;   // column group: cols cg*4 .. cg*4+3
  int ng = tid >> 5;   // node group 0..7
  int nb = blockIdx.x * 64 + ng * 8;

  float acc[8][4];
#pragma unroll
  for (int r = 0; r < 8; ++r)
#pragma unroll
    for (int j = 0; j < 4; ++j) acc[r][j] = 0.f;

  for (int phase = 0; phase < 2; ++phase) {
    const float* U = phase ? x : agg;
    const float* W = phase ? W1r : W1l;
    const float* up[8];
#pragma unroll
    for (int r = 0; r < 8; ++r) {
      int nn = nb + r;
      if (nn > n - 1) nn = n - 1;  // clamp: loads valid, stores guarded below
      up[r] = U + (size_t)nn * DIM;
    }
    for (int k = 0; k < DIM; k += 4) {
      float4 w0 = *(const float4*)(W + (size_t)(k + 0) * DIM + cg * 4);
      float4 w1 = *(const float4*)(W + (size_t)(k + 1) * DIM + cg * 4);
      float4 w2 = *(const float4*)(W + (size_t)(k + 2) * DIM + cg * 4);
      float4 w3 = *(const float4*)(W + (size_t)(k + 3) * DIM + cg * 4);
#pragma unroll
      for (int r = 0; r < 8; ++r) {
        float4 u = *(const float4*)(up[r] + k);
        acc[r][0] += u.x * w0.x + u.y * w1.x + u.z * w2.x + u.w * w3.x;
        acc[r][1] += u.x * w0.y + u.y * w1.y + u.z * w2.y + u.w * w3.y;
        acc[r][2] += u.x * w0.z + u.y * w1.z + u.z * w2.z + u.w * w3.z;
        acc[r][3] += u.x * w0.w + u.y * w1.w + u.z * w2.w + u.w * w3.w;
      }
    }
  }

  float4 bv = *(const float4*)(b1 + cg * 4);
  float4 wl = *(const float4*)(w2l + cg * 4);
  float4 wr = *(const float4*)(w2r + cg * 4);
#pragma unroll
  for (int r = 0; r < 8; ++r) {
    float h0 = fmaxf(acc[r][0] + bv.x, 0.f);
    float h1 = fmaxf(acc[r][1] + bv.y, 0.f);
    float h2 = fmaxf(acc[r][2] + bv.z, 0.f);
    float h3 = fmaxf(acc[r][3] + bv.w, 0.f);
    float sp = h0 * wl.x + h1 * wl.y + h2 * wl.z + h3 * wl.w;
    float tp = h0 * wr.x + h1 * wr.y + h2 * wr.z + h3 * wr.w;
    // reduce across the 32 lanes sharing this node group (lanes [0..31] and
    // [32..63] of a wave are distinct groups; xor masks < 32 stay inside)
#pragma unroll
    for (int m = 1; m < 32; m <<= 1) {
      sp += __shfl_xor(sp, m, 64);
      tp += __shfl_xor(tp, m, 64);
    }
    int nn = nb + r;
    if (cg == 0 && nn < n) {
      sbuf[nn] = sp;
      tbuf[nn] = tp;
    }
  }
}

// ---------------------------------------------------------------------------
// Layer-2: out[i] = mean_{j in N(i)} s[j] + b2 + t[i]
// Edge-parallel scalar atomics (4 B/edge), then per-node finalize.
// ---------------------------------------------------------------------------
__global__ __launch_bounds__(256) void k_edge2(const int* __restrict__ src,
                                               const int* __restrict__ dst,
                                               const float* __restrict__ s,
                                               float* __restrict__ out, int E) {
  int e = blockIdx.x * 256 + threadIdx.x;
  if (e < E) atomicAdd(&out[dst[e]], s[src[e]]);
}

__global__ __launch_bounds__(256) void k_final(float* __restrict__ out,
                                               const int* __restrict__ rowptr,
                                               const float* __restrict__ t,
                                               const float* __restrict__ b2,
                                               int n) {
  int i = blockIdx.x * 256 + threadIdx.x;
  if (i < n) {
    int d = rowptr[i + 1] - rowptr[i];
    out[i] = out[i] / (float)max(d, 1) + b2[0] + t[i];
  }
}

// ---------------------------------------------------------------------------

extern "C" void kernel_launch(void* const* d_in, const int* in_sizes, int n_in,
                              void* d_out, int out_size, void* d_ws,
                              size_t ws_size, hipStream_t stream) {
  const float* x   = (const float*)d_in[0];
  const int*   ei  = (const int*)d_in[1];
  const float* W1l = (const float*)d_in[2];
  const float* b1  = (const float*)d_in[3];
  const float* W1r = (const float*)d_in[4];
  const float* w2l = (const float*)d_in[5];
  const float* b2  = (const float*)d_in[6];
  const float* w2r = (const float*)d_in[7];
  float* out = (float*)d_out;

  int n = in_sizes[0] / DIM;  // 50000
  int E = in_sizes[1] / 2;    // 600000
  const int* src = ei;
  const int* dst = ei + E;

  // workspace carve-out (~29 MB)
  char* ws = (char*)d_ws;
  size_t off = 0;
  auto take = [&](size_t bytes) -> void* {
    void* p = ws + off;
    off = (off + bytes + 511) & ~(size_t)511;
    return p;
  };
  int*   deg    = (int*)take((size_t)n * 4);
  int*   rowptr = (int*)take((size_t)(n + 1) * 4);
  int*   cursor = (int*)take((size_t)n * 4);
  int*   col    = (int*)take((size_t)E * 4);
  float* agg    = (float*)take((size_t)n * DIM * 4);
  float* sbuf   = (float*)take((size_t)n * 4);
  float* tbuf   = (float*)take((size_t)n * 4);
  (void)ws_size; (void)n_in; (void)out_size;

  hipMemsetAsync(deg, 0, (size_t)n * 4, stream);
  hipMemsetAsync(out, 0, (size_t)n * 4, stream);

  int eb = (E + 255) / 256;
  k_count<<<eb, 256, 0, stream>>>(dst, deg, E);
  k_scan<<<1, 1024, 0, stream>>>(deg, rowptr, cursor, n);
  k_fill<<<eb, 256, 0, stream>>>(src, dst, cursor, col, E);
  k_agg<<<(n + 1) / 2, 256, 0, stream>>>(x, rowptr, col, agg, n);
  k_gemm<<<(n + 63) / 64, 256, 0, stream>>>(agg, x, W1l, W1r, b1, w2l, w2r,
                                            sbuf, tbuf, n);
  k_edge2<<<eb, 256, 0, stream>>>(src, dst, sbuf, out, E);
  k_final<<<(n + 255) / 256, 256, 0, stream>>>(out, rowptr, tbuf, b2, n);
}

// Round 2
// 299.362 us; speedup vs baseline: 1.4590x; 1.4590x over previous
//
#include <hip/hip_runtime.h>

#define DIM 128

// ---------------------------------------------------------------------------
// CSR build: count degrees -> 3-phase parallel exclusive scan -> fill cols
// ---------------------------------------------------------------------------

__global__ __launch_bounds__(256) void k_count(const int* __restrict__ dst,
                                               int* __restrict__ deg, int E) {
  int e = blockIdx.x * 256 + threadIdx.x;
  if (e < E) atomicAdd(&deg[dst[e]], 1);
}

// Phase 1: per-block (256-elem) sums, coalesced.
__global__ __launch_bounds__(256) void k_scan1(const int* __restrict__ deg,
                                               int* __restrict__ part, int n) {
  __shared__ int red[256];
  int t = threadIdx.x;
  int i = blockIdx.x * 256 + t;
  red[t] = (i < n) ? deg[i] : 0;
  __syncthreads();
  for (int off = 128; off > 0; off >>= 1) {
    if (t < off) red[t] += red[t + off];
    __syncthreads();
  }
  if (t == 0) part[blockIdx.x] = red[0];
}

// Phase 2: exclusive scan of <=256 block partials in one block.
__global__ __launch_bounds__(256) void k_scan2(int* __restrict__ part, int nb) {
  __shared__ int s[256];
  int t = threadIdx.x;
  int v = (t < nb) ? part[t] : 0;
  s[t] = v;
  __syncthreads();
  for (int off = 1; off < 256; off <<= 1) {
    int u = (t >= off) ? s[t - off] : 0;
    __syncthreads();
    s[t] += u;
    __syncthreads();
  }
  if (t < nb) part[t] = s[t] - v;  // exclusive
}

// Phase 3: per-block exclusive scan + block offset -> rowptr/cursor.
// rowptr[n] == E analytically (every edge increments exactly one degree).
__global__ __launch_bounds__(256) void k_scan3(const int* __restrict__ deg,
                                               const int* __restrict__ part,
                                               int* __restrict__ rowptr,
                                               int* __restrict__ cursor,
                                               int n, int E) {
  __shared__ int s[256];
  int t = threadIdx.x;
  int i = blockIdx.x * 256 + t;
  int v = (i < n) ? deg[i] : 0;
  s[t] = v;
  __syncthreads();
  for (int off = 1; off < 256; off <<= 1) {
    int u = (t >= off) ? s[t - off] : 0;
    __syncthreads();
    s[t] += u;
    __syncthreads();
  }
  int excl = s[t] - v + part[blockIdx.x];
  if (i < n) {
    rowptr[i] = excl;
    cursor[i] = excl;
  }
  if (i == 0) rowptr[n] = E;
}

__global__ __launch_bounds__(256) void k_fill(const int* __restrict__ src,
                                              const int* __restrict__ dst,
                                              int* __restrict__ cursor,
                                              int* __restrict__ col, int E) {
  int e = blockIdx.x * 256 + threadIdx.x;
  if (e < E) {
    int p = atomicAdd(&cursor[dst[e]], 1);
    col[p] = src[e];
  }
}

// ---------------------------------------------------------------------------
// Layer-1 aggregation: agg[i] = mean_{j in N(i)} x[j]   (CSR gather-sum)
// 2 nodes per 256-thread block; 128 lanes = one feature row (coalesced).
// ---------------------------------------------------------------------------
__global__ __launch_bounds__(256) void k_agg(const float* __restrict__ x,
                                             const int* __restrict__ rowptr,
                                             const int* __restrict__ col,
                                             float* __restrict__ agg, int n) {
  int node = blockIdx.x * 2 + (threadIdx.x >> 7);
  int c = threadIdx.x & 127;
  if (node >= n) return;
  int b = rowptr[node], e = rowptr[node + 1];
  float a0 = 0.f, a1 = 0.f, a2 = 0.f, a3 = 0.f;
  int i = b;
  for (; i + 4 <= e; i += 4) {
    int c0 = col[i], c1 = col[i + 1], c2 = col[i + 2], c3 = col[i + 3];
    a0 += x[(size_t)c0 * DIM + c];
    a1 += x[(size_t)c1 * DIM + c];
    a2 += x[(size_t)c2 * DIM + c];
    a3 += x[(size_t)c3 * DIM + c];
  }
  for (; i < e; ++i) a0 += x[(size_t)col[i] * DIM + c];
  float inv = 1.0f / (float)max(e - b, 1);
  agg[(size_t)node * DIM + c] = (a0 + a1 + a2 + a3) * inv;
}

// ---------------------------------------------------------------------------
// Fused layer-1 GEMM + layer-2 projections (h never materialized):
//   h[n] = relu(agg[n] @ W1_l + x[n] @ W1_r + b1)
//   s[n] = h[n] . w2_l ;  t[n] = h[n] . w2_r
// Tile: 64 nodes x 128 cols per 256-thread block; thread = 8 nodes x 4 cols.
// ---------------------------------------------------------------------------
__global__ __launch_bounds__(256) void k_gemm(const float* __restrict__ agg,
                                              const float* __restrict__ x,
                                              const float* __restrict__ W1l,
                                              const float* __restrict__ W1r,
                                              const float* __restrict__ b1,
                                              const float* __restrict__ w2l,
                                              const float* __restrict__ w2r,
                                              float* __restrict__ sbuf,
                                              float* __restrict__ tbuf, int n) {
  int tid = threadIdx.x;
  int cg = tid & 31;   // column group: cols cg*4 .. cg*4+3
  int ng = tid >> 5;   // node group 0..7
  int nb = blockIdx.x * 64 + ng * 8;

  float acc[8][4];
#pragma unroll
  for (int r = 0; r < 8; ++r)
#pragma unroll
    for (int j = 0; j < 4; ++j) acc[r][j] = 0.f;

  for (int phase = 0; phase < 2; ++phase) {
    const float* U = phase ? x : agg;
    const float* W = phase ? W1r : W1l;
    const float* up[8];
#pragma unroll
    for (int r = 0; r < 8; ++r) {
      int nn = nb + r;
      if (nn > n - 1) nn = n - 1;  // clamp: loads valid, stores guarded below
      up[r] = U + (size_t)nn * DIM;
    }
    for (int k = 0; k < DIM; k += 4) {
      float4 w0 = *(const float4*)(W + (size_t)(k + 0) * DIM + cg * 4);
      float4 w1 = *(const float4*)(W + (size_t)(k + 1) * DIM + cg * 4);
      float4 w2 = *(const float4*)(W + (size_t)(k + 2) * DIM + cg * 4);
      float4 w3 = *(const float4*)(W + (size_t)(k + 3) * DIM + cg * 4);
#pragma unroll
      for (int r = 0; r < 8; ++r) {
        float4 u = *(const float4*)(up[r] + k);
        acc[r][0] += u.x * w0.x + u.y * w1.x + u.z * w2.x + u.w * w3.x;
        acc[r][1] += u.x * w0.y + u.y * w1.y + u.z * w2.y + u.w * w3.y;
        acc[r][2] += u.x * w0.z + u.y * w1.z + u.z * w2.z + u.w * w3.z;
        acc[r][3] += u.x * w0.w + u.y * w1.w + u.z * w2.w + u.w * w3.w;
      }
    }
  }

  float4 bv = *(const float4*)(b1 + cg * 4);
  float4 wl = *(const float4*)(w2l + cg * 4);
  float4 wr = *(const float4*)(w2r + cg * 4);
#pragma unroll
  for (int r = 0; r < 8; ++r) {
    float h0 = fmaxf(acc[r][0] + bv.x, 0.f);
    float h1 = fmaxf(acc[r][1] + bv.y, 0.f);
    float h2 = fmaxf(acc[r][2] + bv.z, 0.f);
    float h3 = fmaxf(acc[r][3] + bv.w, 0.f);
    float sp = h0 * wl.x + h1 * wl.y + h2 * wl.z + h3 * wl.w;
    float tp = h0 * wr.x + h1 * wr.y + h2 * wr.z + h3 * wr.w;
    // reduce across the 32 lanes of this node group (xor<32 stays in half-wave)
#pragma unroll
    for (int m = 1; m < 32; m <<= 1) {
      sp += __shfl_xor(sp, m, 64);
      tp += __shfl_xor(tp, m, 64);
    }
    int nn = nb + r;
    if (cg == 0 && nn < n) {
      sbuf[nn] = sp;
      tbuf[nn] = tp;
    }
  }
}

// ---------------------------------------------------------------------------
// Layer-2 via CSR gather (no atomics): out[i] = mean_{j} s[col[j]] + b2 + t[i]
// ---------------------------------------------------------------------------
__global__ __launch_bounds__(256) void k_out(const float* __restrict__ s,
                                             const int* __restrict__ rowptr,
                                             const int* __restrict__ col,
                                             const float* __restrict__ t,
                                             const float* __restrict__ b2,
                                             float* __restrict__ out, int n) {
  int i = blockIdx.x * 256 + threadIdx.x;
  if (i >= n) return;
  int b = rowptr[i], e = rowptr[i + 1];
  float a0 = 0.f, a1 = 0.f, a2 = 0.f, a3 = 0.f;
  int j = b;
  for (; j + 4 <= e; j += 4) {
    a0 += s[col[j]];
    a1 += s[col[j + 1]];
    a2 += s[col[j + 2]];
    a3 += s[col[j + 3]];
  }
  for (; j < e; ++j) a0 += s[col[j]];
  float sum = a0 + a1 + a2 + a3;
  out[i] = sum / (float)max(e - b, 1) + b2[0] + t[i];
}

// ---------------------------------------------------------------------------

extern "C" void kernel_launch(void* const* d_in, const int* in_sizes, int n_in,
                              void* d_out, int out_size, void* d_ws,
                              size_t ws_size, hipStream_t stream) {
  const float* x   = (const float*)d_in[0];
  const int*   ei  = (const int*)d_in[1];
  const float* W1l = (const float*)d_in[2];
  const float* b1  = (const float*)d_in[3];
  const float* W1r = (const float*)d_in[4];
  const float* w2l = (const float*)d_in[5];
  const float* b2  = (const float*)d_in[6];
  const float* w2r = (const float*)d_in[7];
  float* out = (float*)d_out;

  int n = in_sizes[0] / DIM;  // 50000
  int E = in_sizes[1] / 2;    // 600000
  const int* src = ei;
  const int* dst = ei + E;

  // workspace carve-out (~29 MB)
  char* ws = (char*)d_ws;
  size_t off = 0;
  auto take = [&](size_t bytes) -> void* {
    void* p = ws + off;
    off = (off + bytes + 511) & ~(size_t)511;
    return p;
  };
  int*   deg    = (int*)take((size_t)n * 4);
  int*   rowptr = (int*)take((size_t)(n + 1) * 4);
  int*   cursor = (int*)take((size_t)n * 4);
  int*   col    = (int*)take((size_t)E * 4);
  int*   part   = (int*)take(1024);
  float* agg    = (float*)take((size_t)n * DIM * 4);
  float* sbuf   = (float*)take((size_t)n * 4);
  float* tbuf   = (float*)take((size_t)n * 4);
  (void)ws_size; (void)n_in; (void)out_size;

  hipMemsetAsync(deg, 0, (size_t)n * 4, stream);

  int eb = (E + 255) / 256;
  int nb = (n + 255) / 256;  // 196 blocks <= 256 (k_scan2 single-block limit)
  k_count<<<eb, 256, 0, stream>>>(dst, deg, E);
  k_scan1<<<nb, 256, 0, stream>>>(deg, part, n);
  k_scan2<<<1, 256, 0, stream>>>(part, nb);
  k_scan3<<<nb, 256, 0, stream>>>(deg, part, rowptr, cursor, n, E);
  k_fill<<<eb, 256, 0, stream>>>(src, dst, cursor, col, E);
  k_agg<<<(n + 1) / 2, 256, 0, stream>>>(x, rowptr, col, agg, n);
  k_gemm<<<(n + 63) / 64, 256, 0, stream>>>(agg, x, W1l, W1r, b1, w2l, w2r,
                                            sbuf, tbuf, n);
  k_out<<<nb, 256, 0, stream>>>(sbuf, rowptr, col, tbuf, b2, out, n);
}

// Round 3
// 239.757 us; speedup vs baseline: 1.8217x; 1.2486x over previous
//
#include <hip/hip_runtime.h>

#define DIM 128

typedef __attribute__((ext_vector_type(2))) _Float16 f16x2;
typedef __attribute__((ext_vector_type(4))) _Float16 f16x4;
typedef __attribute__((ext_vector_type(8))) _Float16 f16x8;
typedef __attribute__((ext_vector_type(4))) float f32x4;

// ---------------------------------------------------------------------------
// CSR build: count degrees -> 3-phase parallel exclusive scan -> fill cols
// ---------------------------------------------------------------------------

__global__ __launch_bounds__(256) void k_count(const int* __restrict__ dst,
                                               int* __restrict__ deg, int E) {
  int e = blockIdx.x * 256 + threadIdx.x;
  if (e < E) atomicAdd(&deg[dst[e]], 1);
}

__global__ __launch_bounds__(256) void k_scan1(const int* __restrict__ deg,
                                               int* __restrict__ part, int n) {
  __shared__ int red[256];
  int t = threadIdx.x;
  int i = blockIdx.x * 256 + t;
  red[t] = (i < n) ? deg[i] : 0;
  __syncthreads();
  for (int off = 128; off > 0; off >>= 1) {
    if (t < off) red[t] += red[t + off];
    __syncthreads();
  }
  if (t == 0) part[blockIdx.x] = red[0];
}

__global__ __launch_bounds__(256) void k_scan2(int* __restrict__ part, int nb) {
  __shared__ int s[256];
  int t = threadIdx.x;
  int v = (t < nb) ? part[t] : 0;
  s[t] = v;
  __syncthreads();
  for (int off = 1; off < 256; off <<= 1) {
    int u = (t >= off) ? s[t - off] : 0;
    __syncthreads();
    s[t] += u;
    __syncthreads();
  }
  if (t < nb) part[t] = s[t] - v;  // exclusive
}

// Phase 3: rowptr + cursor (cursor aliases deg: each thread reads deg[i]
// before writing cursor[i]; no cross-thread hazard).
__global__ __launch_bounds__(256) void k_scan3(const int* __restrict__ deg,
                                               const int* __restrict__ part,
                                               int* __restrict__ rowptr,
                                               int* __restrict__ cursor,
                                               int n, int E) {
  __shared__ int s[256];
  int t = threadIdx.x;
  int i = blockIdx.x * 256 + t;
  int v = (i < n) ? deg[i] : 0;
  s[t] = v;
  __syncthreads();
  for (int off = 1; off < 256; off <<= 1) {
    int u = (t >= off) ? s[t - off] : 0;
    __syncthreads();
    s[t] += u;
    __syncthreads();
  }
  int excl = s[t] - v + part[blockIdx.x];
  if (i < n) {
    rowptr[i] = excl;
    cursor[i] = excl;
  }
  if (i == 0) rowptr[n] = E;
}

__global__ __launch_bounds__(256) void k_fill(const int* __restrict__ src,
                                              const int* __restrict__ dst,
                                              int* __restrict__ cursor,
                                              int* __restrict__ col, int E) {
  int e = blockIdx.x * 256 + threadIdx.x;
  if (e < E) {
    int p = atomicAdd(&cursor[dst[e]], 1);
    col[p] = src[e];
  }
}

// ---------------------------------------------------------------------------
// x -> f16 copy (for MFMA A operand, phase 2)
// ---------------------------------------------------------------------------
__global__ __launch_bounds__(256) void k_cvt_x(const float* __restrict__ x,
                                               _Float16* __restrict__ xh,
                                               int n4) {
  int i = blockIdx.x * 256 + threadIdx.x;
  if (i >= n4) return;
  float4 v = ((const float4*)x)[i];
  f16x4 o;
  o.x = (_Float16)v.x; o.y = (_Float16)v.y;
  o.z = (_Float16)v.z; o.w = (_Float16)v.w;
  ((f16x4*)xh)[i] = o;
}

// Wt[n][k] f16, k in [0,256): k<128 -> W1l[k][n], else W1r[k-128][n]
__global__ __launch_bounds__(256) void k_cvt_w(const float* __restrict__ W1l,
                                               const float* __restrict__ W1r,
                                               _Float16* __restrict__ Wt) {
  int idx = blockIdx.x * 256 + threadIdx.x;  // 32768 total
  int nn = idx >> 8, k = idx & 255;
  float v = (k < 128) ? W1l[(size_t)k * 128 + nn]
                      : W1r[(size_t)(k - 128) * 128 + nn];
  Wt[(size_t)nn * 256 + k] = (_Float16)v;
}

// ---------------------------------------------------------------------------
// Layer-1 aggregation: aggh[i] = (f16) mean_{j in N(i)} x[j]
// 1 wave per node (lane = 2 cols via float2); 4 nodes/block -> 16 rows in
// flight per block for latency hiding.
// ---------------------------------------------------------------------------
__global__ __launch_bounds__(256) void k_agg(const float* __restrict__ x,
                                             const int* __restrict__ rowptr,
                                             const int* __restrict__ col,
                                             _Float16* __restrict__ aggh,
                                             int n) {
  int node = blockIdx.x * 4 + (threadIdx.x >> 6);
  int lane = threadIdx.x & 63;
  if (node >= n) return;
  int b = rowptr[node], e = rowptr[node + 1];
  float2 a0 = {0.f, 0.f}, a1 = {0.f, 0.f}, a2 = {0.f, 0.f}, a3 = {0.f, 0.f};
  int i = b;
  for (; i + 4 <= e; i += 4) {
    int c0 = col[i], c1 = col[i + 1], c2 = col[i + 2], c3 = col[i + 3];
    float2 v0 = *(const float2*)(x + (size_t)c0 * DIM + lane * 2);
    float2 v1 = *(const float2*)(x + (size_t)c1 * DIM + lane * 2);
    float2 v2 = *(const float2*)(x + (size_t)c2 * DIM + lane * 2);
    float2 v3 = *(const float2*)(x + (size_t)c3 * DIM + lane * 2);
    a0.x += v0.x; a0.y += v0.y;
    a1.x += v1.x; a1.y += v1.y;
    a2.x += v2.x; a2.y += v2.y;
    a3.x += v3.x; a3.y += v3.y;
  }
  for (; i < e; ++i) {
    float2 v = *(const float2*)(x + (size_t)col[i] * DIM + lane * 2);
    a0.x += v.x; a0.y += v.y;
  }
  float inv = 1.0f / (float)max(e - b, 1);
  f16x2 o;
  o.x = (_Float16)((a0.x + a1.x + a2.x + a3.x) * inv);
  o.y = (_Float16)((a0.y + a1.y + a2.y + a3.y) * inv);
  ((f16x2*)aggh)[(size_t)node * 64 + lane] = o;
}

// ---------------------------------------------------------------------------
// MFMA f16 GEMM + fused epilogue (h never materialized):
//   h = relu([agg|x] @ [W1l;W1r] + b1);  s = h.w2l;  t = h.w2r
// Block: 16 nodes x 128 cols, 4 waves; wave = 16x32 (2 MFMA col-tiles),
// K = 256 in 8 steps of mfma_f32_16x16x32_f16.
// A frag: A[m=lane&15][k=quad*8+j]; B frag: Wt[n=lane&15(+c0)][k=quad*8+j];
// D: col=lane&15, row=quad*4+reg.
// ---------------------------------------------------------------------------
__global__ __launch_bounds__(256) void k_gemm(const _Float16* __restrict__ aggh,
                                              const _Float16* __restrict__ xh,
                                              const _Float16* __restrict__ Wt,
                                              const float* __restrict__ b1,
                                              const float* __restrict__ w2l,
                                              const float* __restrict__ w2r,
                                              float* __restrict__ sbuf,
                                              float* __restrict__ tbuf, int n) {
  __shared__ float s_l[16], t_l[16];
  int tid = threadIdx.x;
  int wv = tid >> 6;
  int lane = tid & 63;
  int q = lane >> 4;
  int l16 = lane & 15;
  int nb = blockIdx.x * 16;
  if (nb >= n) return;
  int c0 = wv * 32;

  if (tid < 16) { s_l[tid] = 0.f; t_l[tid] = 0.f; }
  __syncthreads();

  f32x4 acc0 = {0.f, 0.f, 0.f, 0.f}, acc1 = {0.f, 0.f, 0.f, 0.f};
  const _Float16* arow0 = aggh + (size_t)(nb + l16) * 128 + q * 8;
  const _Float16* arow1 = xh + (size_t)(nb + l16) * 128 + q * 8;
  const _Float16* bp0 = Wt + (size_t)(c0 + l16) * 256 + q * 8;
  const _Float16* bp1 = Wt + (size_t)(c0 + 16 + l16) * 256 + q * 8;

#pragma unroll
  for (int s = 0; s < 8; ++s) {
    const _Float16* ap = (s < 4) ? (arow0 + s * 32) : (arow1 + (s - 4) * 32);
    f16x8 a = *(const f16x8*)ap;
    f16x8 b0 = *(const f16x8*)(bp0 + s * 32);
    f16x8 b1v = *(const f16x8*)(bp1 + s * 32);
    acc0 = __builtin_amdgcn_mfma_f32_16x16x32_f16(a, b0, acc0, 0, 0, 0);
    acc1 = __builtin_amdgcn_mfma_f32_16x16x32_f16(a, b1v, acc1, 0, 0, 0);
  }

  float bia0 = b1[c0 + l16], bia1 = b1[c0 + 16 + l16];
  float wl0 = w2l[c0 + l16], wl1 = w2l[c0 + 16 + l16];
  float wr0 = w2r[c0 + l16], wr1 = w2r[c0 + 16 + l16];
#pragma unroll
  for (int r = 0; r < 4; ++r) {
    int row = q * 4 + r;
    float h0 = fmaxf(acc0[r] + bia0, 0.f);
    float h1 = fmaxf(acc1[r] + bia1, 0.f);
    float sp = h0 * wl0 + h1 * wl1;
    float tp = h0 * wr0 + h1 * wr1;
#pragma unroll
    for (int m = 1; m < 16; m <<= 1) {  // reduce 16 cols within quad
      sp += __shfl_xor(sp, m, 64);
      tp += __shfl_xor(tp, m, 64);
    }
    if (l16 == 0) {
      atomicAdd(&s_l[row], sp);
      atomicAdd(&t_l[row], tp);
    }
  }
  __syncthreads();
  if (tid < 16 && nb + tid < n) {
    sbuf[nb + tid] = s_l[tid];
    tbuf[nb + tid] = t_l[tid];
  }
}

// ---------------------------------------------------------------------------
// Layer-2 via CSR gather: out[i] = mean_j s[col[j]] + b2 + t[i]
// ---------------------------------------------------------------------------
__global__ __launch_bounds__(256) void k_out(const float* __restrict__ s,
                                             const int* __restrict__ rowptr,
                                             const int* __restrict__ col,
                                             const float* __restrict__ t,
                                             const float* __restrict__ b2,
                                             float* __restrict__ out, int n) {
  int i = blockIdx.x * 256 + threadIdx.x;
  if (i >= n) return;
  int b = rowptr[i], e = rowptr[i + 1];
  float a0 = 0.f, a1 = 0.f, a2 = 0.f, a3 = 0.f;
  int j = b;
  for (; j + 4 <= e; j += 4) {
    a0 += s[col[j]];
    a1 += s[col[j + 1]];
    a2 += s[col[j + 2]];
    a3 += s[col[j + 3]];
  }
  for (; j < e; ++j) a0 += s[col[j]];
  float sum = a0 + a1 + a2 + a3;
  out[i] = sum / (float)max(e - b, 1) + b2[0] + t[i];
}

// ---------------------------------------------------------------------------

extern "C" void kernel_launch(void* const* d_in, const int* in_sizes, int n_in,
                              void* d_out, int out_size, void* d_ws,
                              size_t ws_size, hipStream_t stream) {
  const float* x   = (const float*)d_in[0];
  const int*   ei  = (const int*)d_in[1];
  const float* W1l = (const float*)d_in[2];
  const float* b1  = (const float*)d_in[3];
  const float* W1r = (const float*)d_in[4];
  const float* w2l = (const float*)d_in[5];
  const float* b2  = (const float*)d_in[6];
  const float* w2r = (const float*)d_in[7];
  float* out = (float*)d_out;

  int n = in_sizes[0] / DIM;  // 50000
  int E = in_sizes[1] / 2;    // 600000
  const int* src = ei;
  const int* dst = ei + E;

  // workspace carve-out (~16.4 MB)
  char* ws = (char*)d_ws;
  size_t off = 0;
  auto take = [&](size_t bytes) -> void* {
    void* p = ws + off;
    off = (off + bytes + 511) & ~(size_t)511;
    return p;
  };
  int*      deg    = (int*)take((size_t)n * 4);        // aliased as cursor
  int*      rowptr = (int*)take((size_t)(n + 1) * 4);
  int*      col    = (int*)take((size_t)E * 4);
  int*      part   = (int*)take(1024);
  _Float16* aggh   = (_Float16*)take((size_t)n * DIM * 2);
  _Float16* xh     = (_Float16*)take((size_t)n * DIM * 2);
  _Float16* Wt     = (_Float16*)take((size_t)DIM * 256 * 2);
  float*    sbuf   = (float*)take((size_t)n * 4);
  float*    tbuf   = (float*)take((size_t)n * 4);
  int* cursor = deg;
  (void)ws_size; (void)n_in; (void)out_size;

  hipMemsetAsync(deg, 0, (size_t)n * 4, stream);

  int eb = (E + 255) / 256;
  int nbk = (n + 255) / 256;  // 196 blocks <= 256 (k_scan2 single-block limit)
  k_count<<<eb, 256, 0, stream>>>(dst, deg, E);
  k_scan1<<<nbk, 256, 0, stream>>>(deg, part, n);
  k_scan2<<<1, 256, 0, stream>>>(part, nbk);
  k_scan3<<<nbk, 256, 0, stream>>>(deg, part, rowptr, cursor, n, E);
  k_fill<<<eb, 256, 0, stream>>>(src, dst, cursor, col, E);
  k_cvt_x<<<(n * DIM / 4 + 255) / 256, 256, 0, stream>>>(x, xh, n * DIM / 4);
  k_cvt_w<<<(DIM * 256 + 255) / 256, 256, 0, stream>>>(W1l, W1r, Wt);
  k_agg<<<(n + 3) / 4, 256, 0, stream>>>(x, rowptr, col, aggh, n);
  k_gemm<<<(n + 15) / 16, 256, 0, stream>>>(aggh, xh, Wt, b1, w2l, w2r,
                                            sbuf, tbuf, n);
  k_out<<<nbk, 256, 0, stream>>>(sbuf, rowptr, col, tbuf, b2, out, n);
}

// Round 4
// 212.457 us; speedup vs baseline: 2.0557x; 1.1285x over previous
//
#include <hip/hip_runtime.h>

#define DIM 128

typedef __attribute__((ext_vector_type(2))) _Float16 f16x2;
typedef __attribute__((ext_vector_type(4))) _Float16 f16x4;
typedef __attribute__((ext_vector_type(8))) _Float16 f16x8;
typedef __attribute__((ext_vector_type(4))) float f32x4;

// ---------------------------------------------------------------------------
// CSR build: count degrees -> 3-phase parallel exclusive scan -> fill cols
// ---------------------------------------------------------------------------

__global__ __launch_bounds__(256) void k_count(const int* __restrict__ dst,
                                               int* __restrict__ deg, int E) {
  int e = blockIdx.x * 256 + threadIdx.x;
  if (e < E) atomicAdd(&deg[dst[e]], 1);
}

__global__ __launch_bounds__(256) void k_scan1(const int* __restrict__ deg,
                                               int* __restrict__ part, int n) {
  __shared__ int red[256];
  int t = threadIdx.x;
  int i = blockIdx.x * 256 + t;
  red[t] = (i < n) ? deg[i] : 0;
  __syncthreads();
  for (int off = 128; off > 0; off >>= 1) {
    if (t < off) red[t] += red[t + off];
    __syncthreads();
  }
  if (t == 0) part[blockIdx.x] = red[0];
}

__global__ __launch_bounds__(256) void k_scan2(int* __restrict__ part, int nb) {
  __shared__ int s[256];
  int t = threadIdx.x;
  int v = (t < nb) ? part[t] : 0;
  s[t] = v;
  __syncthreads();
  for (int off = 1; off < 256; off <<= 1) {
    int u = (t >= off) ? s[t - off] : 0;
    __syncthreads();
    s[t] += u;
    __syncthreads();
  }
  if (t < nb) part[t] = s[t] - v;  // exclusive
}

// Phase 3: rowptr + cursor (cursor aliases deg: each thread reads deg[i]
// before writing cursor[i]; no cross-thread hazard).
__global__ __launch_bounds__(256) void k_scan3(const int* __restrict__ deg,
                                               const int* __restrict__ part,
                                               int* __restrict__ rowptr,
                                               int* __restrict__ cursor,
                                               int n, int E) {
  __shared__ int s[256];
  int t = threadIdx.x;
  int i = blockIdx.x * 256 + t;
  int v = (i < n) ? deg[i] : 0;
  s[t] = v;
  __syncthreads();
  for (int off = 1; off < 256; off <<= 1) {
    int u = (t >= off) ? s[t - off] : 0;
    __syncthreads();
    s[t] += u;
    __syncthreads();
  }
  int excl = s[t] - v + part[blockIdx.x];
  if (i < n) {
    rowptr[i] = excl;
    cursor[i] = excl;
  }
  if (i == 0) rowptr[n] = E;
}

__global__ __launch_bounds__(256) void k_fill(const int* __restrict__ src,
                                              const int* __restrict__ dst,
                                              int* __restrict__ cursor,
                                              int* __restrict__ col, int E) {
  int e = blockIdx.x * 256 + threadIdx.x;
  if (e < E) {
    int p = atomicAdd(&cursor[dst[e]], 1);
    col[p] = src[e];
  }
}

// ---------------------------------------------------------------------------
// Fused converts: x (fp32) -> xh (f16), and W1l|W1r -> Wt[n][k] f16 (k<128:
// W1l[k][n], else W1r[k-128][n]).
// ---------------------------------------------------------------------------
__global__ __launch_bounds__(256) void k_cvt(const float* __restrict__ x,
                                             _Float16* __restrict__ xh, int n4,
                                             const float* __restrict__ W1l,
                                             const float* __restrict__ W1r,
                                             _Float16* __restrict__ Wt) {
  int i = blockIdx.x * 256 + threadIdx.x;
  if (i < n4) {
    float4 v = ((const float4*)x)[i];
    f16x4 o;
    o.x = (_Float16)v.x; o.y = (_Float16)v.y;
    o.z = (_Float16)v.z; o.w = (_Float16)v.w;
    ((f16x4*)xh)[i] = o;
  } else {
    int idx = i - n4;
    if (idx < 128 * 256) {
      int nn = idx >> 8, k = idx & 255;
      float v = (k < 128) ? W1l[(size_t)k * 128 + nn]
                          : W1r[(size_t)(k - 128) * 128 + nn];
      Wt[(size_t)nn * 256 + k] = (_Float16)v;
    }
  }
}

// ---------------------------------------------------------------------------
// Layer-1 aggregation from f16: aggh[i] = (f16) mean_{j in N(i)} xh[j]
// 1 wave per node (lane = 2 cols via f16x2, 256 B/edge); 4 nodes/block.
// ---------------------------------------------------------------------------
__global__ __launch_bounds__(256) void k_agg(const _Float16* __restrict__ xh,
                                             const int* __restrict__ rowptr,
                                             const int* __restrict__ col,
                                             _Float16* __restrict__ aggh,
                                             int n) {
  int node = blockIdx.x * 4 + (threadIdx.x >> 6);
  int lane = threadIdx.x & 63;
  if (node >= n) return;
  int b = rowptr[node], e = rowptr[node + 1];
  const f16x2* X = (const f16x2*)xh;
  float ax0 = 0.f, ay0 = 0.f, ax1 = 0.f, ay1 = 0.f;
  float ax2 = 0.f, ay2 = 0.f, ax3 = 0.f, ay3 = 0.f;
  int i = b;
  for (; i + 4 <= e; i += 4) {
    int c0 = col[i], c1 = col[i + 1], c2 = col[i + 2], c3 = col[i + 3];
    f16x2 v0 = X[(size_t)c0 * 64 + lane];
    f16x2 v1 = X[(size_t)c1 * 64 + lane];
    f16x2 v2 = X[(size_t)c2 * 64 + lane];
    f16x2 v3 = X[(size_t)c3 * 64 + lane];
    ax0 += (float)v0.x; ay0 += (float)v0.y;
    ax1 += (float)v1.x; ay1 += (float)v1.y;
    ax2 += (float)v2.x; ay2 += (float)v2.y;
    ax3 += (float)v3.x; ay3 += (float)v3.y;
  }
  for (; i < e; ++i) {
    f16x2 v = X[(size_t)col[i] * 64 + lane];
    ax0 += (float)v.x; ay0 += (float)v.y;
  }
  float inv = 1.0f / (float)max(e - b, 1);
  f16x2 o;
  o.x = (_Float16)((ax0 + ax1 + ax2 + ax3) * inv);
  o.y = (_Float16)((ay0 + ay1 + ay2 + ay3) * inv);
  ((f16x2*)aggh)[(size_t)node * 64 + lane] = o;
}

// ---------------------------------------------------------------------------
// MFMA f16 GEMM + fused epilogue (h never materialized):
//   h = relu([agg|x] @ [W1l;W1r] + b1);  s = h.w2l;  t = h.w2r
// Block: 64 rows x 128 cols, 4 waves in 2x2 (row-half x col-half).
// Wave: 32 rows x 64 cols = 2 row-tiles x 4 col-tiles, K=256 in 8 steps of
// mfma_f32_16x16x32_f16 (8 MFMA/step, 64 total).
// A frag: A[m=lane&15][k=quad*8+j]; B frag: Wt[nn][k] same pattern;
// D: col=lane&15, row=quad*4+reg.
// ---------------------------------------------------------------------------
__global__ __launch_bounds__(256) void k_gemm(const _Float16* __restrict__ aggh,
                                              const _Float16* __restrict__ xh,
                                              const _Float16* __restrict__ Wt,
                                              const float* __restrict__ b1,
                                              const float* __restrict__ w2l,
                                              const float* __restrict__ w2r,
                                              float* __restrict__ sbuf,
                                              float* __restrict__ tbuf, int n) {
  __shared__ float s_l[64], t_l[64];
  int tid = threadIdx.x;
  int wv = tid >> 6;
  int lane = tid & 63;
  int q = lane >> 4;
  int l16 = lane & 15;
  int rh = wv & 1;         // row-half: rows rh*32..rh*32+31
  int ch = wv >> 1;        // col-half: cols ch*64..ch*64+63
  int nb = blockIdx.x * 64;

  if (tid < 64) { s_l[tid] = 0.f; t_l[tid] = 0.f; }
  __syncthreads();

  f32x4 acc[2][4];
#pragma unroll
  for (int rt = 0; rt < 2; ++rt)
#pragma unroll
    for (int ct = 0; ct < 4; ++ct) acc[rt][ct] = (f32x4){0.f, 0.f, 0.f, 0.f};

  // A row pointers (clamped for tail block)
  const _Float16* arow0[2];  // aggh
  const _Float16* arow1[2];  // xh
#pragma unroll
  for (int rt = 0; rt < 2; ++rt) {
    int r = nb + rh * 32 + rt * 16 + l16;
    if (r > n - 1) r = n - 1;
    arow0[rt] = aggh + (size_t)r * 128 + q * 8;
    arow1[rt] = xh + (size_t)r * 128 + q * 8;
  }
  const _Float16* bp[4];
#pragma unroll
  for (int ct = 0; ct < 4; ++ct)
    bp[ct] = Wt + (size_t)(ch * 64 + ct * 16 + l16) * 256 + q * 8;

#pragma unroll
  for (int s = 0; s < 8; ++s) {
    f16x8 a[2], b[4];
#pragma unroll
    for (int rt = 0; rt < 2; ++rt)
      a[rt] = (s < 4) ? *(const f16x8*)(arow0[rt] + s * 32)
                      : *(const f16x8*)(arow1[rt] + (s - 4) * 32);
#pragma unroll
    for (int ct = 0; ct < 4; ++ct) b[ct] = *(const f16x8*)(bp[ct] + s * 32);
#pragma unroll
    for (int rt = 0; rt < 2; ++rt)
#pragma unroll
      for (int ct = 0; ct < 4; ++ct)
        acc[rt][ct] =
            __builtin_amdgcn_mfma_f32_16x16x32_f16(a[rt], b[ct], acc[rt][ct], 0, 0, 0);
  }

  float bia[4], wl[4], wr[4];
#pragma unroll
  for (int ct = 0; ct < 4; ++ct) {
    int c = ch * 64 + ct * 16 + l16;
    bia[ct] = b1[c];
    wl[ct] = w2l[c];
    wr[ct] = w2r[c];
  }

#pragma unroll
  for (int rt = 0; rt < 2; ++rt) {
#pragma unroll
    for (int r = 0; r < 4; ++r) {
      float sp = 0.f, tp = 0.f;
#pragma unroll
      for (int ct = 0; ct < 4; ++ct) {
        float h = fmaxf(acc[rt][ct][r] + bia[ct], 0.f);
        sp += h * wl[ct];
        tp += h * wr[ct];
      }
#pragma unroll
      for (int m = 1; m < 16; m <<= 1) {  // reduce 16 cols; stays within quad
        sp += __shfl_xor(sp, m, 64);
        tp += __shfl_xor(tp, m, 64);
      }
      if (l16 == 0) {
        int row = rh * 32 + rt * 16 + q * 4 + r;
        atomicAdd(&s_l[row], sp);  // two col-halves combine here
        atomicAdd(&t_l[row], tp);
      }
    }
  }
  __syncthreads();
  if (tid < 64 && nb + tid < n) {
    sbuf[nb + tid] = s_l[tid];
    tbuf[nb + tid] = t_l[tid];
  }
}

// ---------------------------------------------------------------------------
// Layer-2 via CSR gather: out[i] = mean_j s[col[j]] + b2 + t[i]
// ---------------------------------------------------------------------------
__global__ __launch_bounds__(256) void k_out(const float* __restrict__ s,
                                             const int* __restrict__ rowptr,
                                             const int* __restrict__ col,
                                             const float* __restrict__ t,
                                             const float* __restrict__ b2,
                                             float* __restrict__ out, int n) {
  int i = blockIdx.x * 256 + threadIdx.x;
  if (i >= n) return;
  int b = rowptr[i], e = rowptr[i + 1];
  float a0 = 0.f, a1 = 0.f, a2 = 0.f, a3 = 0.f;
  int j = b;
  for (; j + 4 <= e; j += 4) {
    a0 += s[col[j]];
    a1 += s[col[j + 1]];
    a2 += s[col[j + 2]];
    a3 += s[col[j + 3]];
  }
  for (; j < e; ++j) a0 += s[col[j]];
  float sum = a0 + a1 + a2 + a3;
  out[i] = sum / (float)max(e - b, 1) + b2[0] + t[i];
}

// ---------------------------------------------------------------------------

extern "C" void kernel_launch(void* const* d_in, const int* in_sizes, int n_in,
                              void* d_out, int out_size, void* d_ws,
                              size_t ws_size, hipStream_t stream) {
  const float* x   = (const float*)d_in[0];
  const int*   ei  = (const int*)d_in[1];
  const float* W1l = (const float*)d_in[2];
  const float* b1  = (const float*)d_in[3];
  const float* W1r = (const float*)d_in[4];
  const float* w2l = (const float*)d_in[5];
  const float* b2  = (const float*)d_in[6];
  const float* w2r = (const float*)d_in[7];
  float* out = (float*)d_out;

  int n = in_sizes[0] / DIM;  // 50000
  int E = in_sizes[1] / 2;    // 600000
  const int* src = ei;
  const int* dst = ei + E;

  // workspace carve-out (~16.4 MB)
  char* ws = (char*)d_ws;
  size_t off = 0;
  auto take = [&](size_t bytes) -> void* {
    void* p = ws + off;
    off = (off + bytes + 511) & ~(size_t)511;
    return p;
  };
  int*      deg    = (int*)take((size_t)n * 4);  // aliased as cursor
  int*      rowptr = (int*)take((size_t)(n + 1) * 4);
  int*      col    = (int*)take((size_t)E * 4);
  int*      part   = (int*)take(1024);
  _Float16* aggh   = (_Float16*)take((size_t)n * DIM * 2);
  _Float16* xh     = (_Float16*)take((size_t)n * DIM * 2);
  _Float16* Wt     = (_Float16*)take((size_t)DIM * 256 * 2);
  float*    sbuf   = (float*)take((size_t)n * 4);
  float*    tbuf   = (float*)take((size_t)n * 4);
  int* cursor = deg;
  (void)ws_size; (void)n_in; (void)out_size;

  hipMemsetAsync(deg, 0, (size_t)n * 4, stream);

  int eb = (E + 255) / 256;
  int nbk = (n + 255) / 256;  // 196 blocks <= 256 (k_scan2 single-block limit)
  int n4 = n * DIM / 4;
  k_count<<<eb, 256, 0, stream>>>(dst, deg, E);
  k_scan1<<<nbk, 256, 0, stream>>>(deg, part, n);
  k_scan2<<<1, 256, 0, stream>>>(part, nbk);
  k_scan3<<<nbk, 256, 0, stream>>>(deg, part, rowptr, cursor, n, E);
  k_fill<<<eb, 256, 0, stream>>>(src, dst, cursor, col, E);
  k_cvt<<<(n4 + 128 * 256 + 255) / 256, 256, 0, stream>>>(x, xh, n4, W1l, W1r, Wt);
  k_agg<<<(n + 3) / 4, 256, 0, stream>>>(xh, rowptr, col, aggh, n);
  k_gemm<<<(n + 63) / 64, 256, 0, stream>>>(aggh, xh, Wt, b1, w2l, w2r,
                                            sbuf, tbuf, n);
  k_out<<<nbk, 256, 0, stream>>>(sbuf, rowptr, col, tbuf, b2, out, n);
}